// Round 9
// baseline (228.916 us; speedup 1.0000x reference)
//
#include <hip/hip_runtime.h>

#define NN 100000
#define NE 800000

typedef __attribute__((ext_vector_type(4))) float f32x4;
typedef __attribute__((ext_vector_type(4))) int   i32x4;
typedef __attribute__((ext_vector_type(8))) unsigned short u16x8;

__device__ __forceinline__ unsigned short f2bf(float f) {
  unsigned u = __float_as_uint(f);
  return (unsigned short)((u + 0x7FFFu + ((u >> 16) & 1u)) >> 16);
}
__device__ __forceinline__ float bf2f(unsigned short b) {
  return __uint_as_float(((unsigned)b) << 16);
}

// ---------------- CSR build ----------------
__global__ void degree_k(const int* __restrict__ dst, int* __restrict__ deg,
                         int* __restrict__ rord) {
  int e = blockIdx.x * 256 + threadIdx.x;
  if (e < NE) rord[e] = atomicAdd(&deg[dst[e]], 1);
}

__global__ __launch_bounds__(256) void scan1_k(const int* __restrict__ deg,
    int* __restrict__ offs, int* __restrict__ bsum, float* __restrict__ inv) {
  __shared__ int s[256];
  int t = threadIdx.x;
  int base = blockIdx.x * 1024 + t * 4;
  int v[4], tsum = 0;
#pragma unroll
  for (int k = 0; k < 4; ++k) {
    int i = base + k;
    v[k] = (i < NN) ? deg[i] : 0;
    tsum += v[k];
    if (i < NN) inv[i] = 1.0f / fmaxf((float)v[k], 1.0f);
  }
  s[t] = tsum; __syncthreads();
  int val = tsum;
#pragma unroll
  for (int off = 1; off < 256; off <<= 1) {
    int x = (t >= off) ? s[t - off] : 0;
    __syncthreads();
    val += x; s[t] = val;
    __syncthreads();
  }
  int excl = val - tsum;
  if (t == 255) bsum[blockIdx.x] = val;
  int run = excl;
#pragma unroll
  for (int k = 0; k < 4; ++k) { int i = base + k; if (i < NN) offs[i] = run; run += v[k]; }
}

__global__ __launch_bounds__(256) void scan2_k(int* __restrict__ bsum, int nb) {
  __shared__ int s[256];
  int t = threadIdx.x;
  int v = (t < nb) ? bsum[t] : 0;
  s[t] = v; __syncthreads();
  int val = v;
#pragma unroll
  for (int off = 1; off < 256; off <<= 1) {
    int x = (t >= off) ? s[t - off] : 0;
    __syncthreads();
    val += x; s[t] = val;
    __syncthreads();
  }
  if (t < nb) bsum[t] = val - v;
}

__global__ __launch_bounds__(256) void scan3_k(int* __restrict__ offs,
    const int* __restrict__ bsum) {
  int base = blockIdx.x * 1024 + threadIdx.x * 4;
  int add = bsum[blockIdx.x];
#pragma unroll
  for (int k = 0; k < 4; ++k) {
    int i = base + k;
    if (i < NN) offs[i] += add;
  }
}

__global__ void fill_k(const int* __restrict__ src, const int* __restrict__ dst,
    const int* __restrict__ offs, const int* __restrict__ rord,
    int* __restrict__ eidx) {
  int e = blockIdx.x * 256 + threadIdx.x;
  if (e < NE) {
    int p = offs[dst[e]] + rord[e];
    __builtin_nontemporal_store(src[e], &eidx[p]);
  }
}

// ---------------- casts ----------------
__global__ __launch_bounds__(256) void cast_x_k(const float* __restrict__ in,
    unsigned short* __restrict__ outb) {
  int i = blockIdx.x * 256 + threadIdx.x;
  if (i >= NN * 128 / 4) return;
  float4 v = *reinterpret_cast<const float4*>(in + (size_t)i * 4);
  ushort4 o;
  o.x = f2bf(v.x); o.y = f2bf(v.y); o.z = f2bf(v.z); o.w = f2bf(v.w);
  *reinterpret_cast<ushort4*>(outb + (size_t)i * 4) = o;
}

__global__ __launch_bounds__(256) void cast_w4_k(const float* __restrict__ Wa,
    const float* __restrict__ Wb, const float* __restrict__ Wc,
    const float* __restrict__ Wd, unsigned short* __restrict__ outb) {
  int i = blockIdx.x * 256 + threadIdx.x;
  if (i >= 4 * 32768) return;
  int seg = i >> 15, off = i & 32767;
  const float* s = (seg < 2) ? (seg == 0 ? Wa : Wb) : (seg == 2 ? Wc : Wd);
  outb[i] = f2bf(s[off]);
}

// ---------------- gather for layer 2 (bf16 table, fp32 accum) ----------------
// 16 lanes/node, 16B/lane; x4 unroll keeps 4 row-loads in flight.
// outf(f32)[node] = bf2f(selfb[node]) + inv*sum(feat[nbr])
__global__ __launch_bounds__(256) void gather2_k(const unsigned short* __restrict__ feat,
    const int* __restrict__ offs, const int* __restrict__ deg,
    const float* __restrict__ inv, const int* __restrict__ eidx,
    const unsigned short* __restrict__ selfb, float* __restrict__ outf) {
  int node = blockIdx.x * 16 + (threadIdx.x >> 4);
  int l = threadIdx.x & 15;
  if (node >= NN) return;
  int st = offs[node], n = deg[node];
  float a[8];
#pragma unroll
  for (int k = 0; k < 8; ++k) a[k] = 0.f;

  int j = 0;
  for (; j + 4 <= n; j += 4) {
    int s0 = eidx[st + j + 0];
    int s1 = eidx[st + j + 1];
    int s2 = eidx[st + j + 2];
    int s3 = eidx[st + j + 3];
    u16x8 r0 = *reinterpret_cast<const u16x8*>(feat + (size_t)s0 * 128 + l * 8);
    u16x8 r1 = *reinterpret_cast<const u16x8*>(feat + (size_t)s1 * 128 + l * 8);
    u16x8 r2 = *reinterpret_cast<const u16x8*>(feat + (size_t)s2 * 128 + l * 8);
    u16x8 r3 = *reinterpret_cast<const u16x8*>(feat + (size_t)s3 * 128 + l * 8);
#pragma unroll
    for (int k = 0; k < 8; ++k)
      a[k] += (bf2f(r0[k]) + bf2f(r1[k])) + (bf2f(r2[k]) + bf2f(r3[k]));
  }
  for (; j < n; ++j) {
    int s = eidx[st + j];
    u16x8 r = *reinterpret_cast<const u16x8*>(feat + (size_t)s * 128 + l * 8);
#pragma unroll
    for (int k = 0; k < 8; ++k) a[k] += bf2f(r[k]);
  }

  float sc = inv[node];
  u16x8 sb = *reinterpret_cast<const u16x8*>(selfb + (size_t)node * 128 + l * 8);
  float4 o0, o1;
  o0.x = bf2f(sb[0]) + sc * a[0]; o0.y = bf2f(sb[1]) + sc * a[1];
  o0.z = bf2f(sb[2]) + sc * a[2]; o0.w = bf2f(sb[3]) + sc * a[3];
  o1.x = bf2f(sb[4]) + sc * a[4]; o1.y = bf2f(sb[5]) + sc * a[5];
  o1.z = bf2f(sb[6]) + sc * a[6]; o1.w = bf2f(sb[7]) + sc * a[7];
  float* po = outf + (size_t)node * 128 + l * 8;
  *reinterpret_cast<float4*>(po) = o0;
  *reinterpret_cast<float4*>(po + 4) = o1;
}

// -------- layer 1 FUSED: gather + MFMA GEMM, persistent (64 rows x 256 cols) --------
// Per panel p (64 nodes): A-tile = [m1 | x_self], staged per-iteration:
//   - Asf half via global_load_lds from xb (pre-swizzled source, linear LDS)
//   - Am1 half computed in-kernel: 4 thr/node gather-mean of xb rows -> swizzled ds_write
// Then h[p] = relu([Am1|Asf] @ [W1l|W1r]^T + b1), bf16 -> outb [NN,256].
// B fragments preloaded once to regs (128 VGPR). 2 blocks/CU; gather of panel p+1
// overlaps co-resident block's MFMA.
__global__ __launch_bounds__(256, 2) void fgemm1_k(
    const unsigned short* __restrict__ xb,
    const int* __restrict__ offs, const int* __restrict__ deg,
    const float* __restrict__ inv, const int* __restrict__ eidx,
    const unsigned short* __restrict__ Wbase, const float* __restrict__ bias,
    unsigned short* __restrict__ outb) {
  __shared__ unsigned short Am1[2][64 * 128];   // 16 KB per buf, row stride 256 B
  __shared__ unsigned short Asf[2][64 * 128];   // 16 KB per buf
  const int t = threadIdx.x;
  const int wave = t >> 6, lane = t & 63;
  const int lhi = lane >> 4, llo = lane & 15;

  // ---- B fragments + bias, loaded once (k-concat: ks<4 -> W1l, ks>=4 -> W1r) ----
  i32x4 bfrag[8][4];
  float bv[4];
#pragma unroll
  for (int fn = 0; fn < 4; ++fn) {
    int c = wave * 64 + fn * 16 + llo;
    const unsigned short* rowp = Wbase + (size_t)c * 128;
    bv[fn] = bias[c];
#pragma unroll
    for (int ks = 0; ks < 8; ++ks) {
      int koff = (ks & 3) * 32 + lhi * 8 + ((ks >= 4) ? 32768 : 0);
      bfrag[ks][fn] = *reinterpret_cast<const i32x4*>(rowp + koff);
    }
  }

  const int gn = t >> 2;        // gather: local node 0..63
  const int gl = t & 3;         // 4 threads/node, 32 bf16 (64 B) each

  auto stage = [&](int buf, int p) {
    const int row0 = p * 64;
    // ---- self half: 16 chunks of 1KB via global_load_lds, swizzled source ----
#pragma unroll
    for (int c = 0; c < 4; ++c) {
      int chunk = wave * 4 + c;
      int tb = chunk * 1024 + lane * 16;
      int r = tb >> 8;                    // 256 B rows
      int cb = tb & 255;
      int cbs = cb ^ ((r & 7) << 4);      // involutive XOR swizzle
      int gr = min(row0 + r, NN - 1);
      __builtin_amdgcn_global_load_lds(
          (const __attribute__((address_space(1))) void*)
              ((const char*)(xb + (size_t)gr * 128) + cbs),
          (__attribute__((address_space(3))) void*)((char*)&Asf[buf][0] + chunk * 1024),
          16, 0, 0);
    }
    // ---- m1 half: gather-mean, 4 thr/node, 32 f32 accum each ----
    int node = row0 + gn;
    bool valid = node < NN;
    int st = 0, cnt = 0;
    float sc = 0.f;
    if (valid) { st = offs[node]; cnt = deg[node]; sc = inv[node]; }
    float a[32];
#pragma unroll
    for (int k = 0; k < 32; ++k) a[k] = 0.f;
    const unsigned short* fb = xb + gl * 32;
    int j = 0;
    for (; j + 2 <= cnt; j += 2) {
      int s0 = eidx[st + j], s1 = eidx[st + j + 1];
      const u16x8* p0 = reinterpret_cast<const u16x8*>(fb + (size_t)s0 * 128);
      const u16x8* p1 = reinterpret_cast<const u16x8*>(fb + (size_t)s1 * 128);
      u16x8 r0[4], r1[4];
#pragma unroll
      for (int q = 0; q < 4; ++q) { r0[q] = p0[q]; r1[q] = p1[q]; }
#pragma unroll
      for (int q = 0; q < 4; ++q)
#pragma unroll
        for (int k = 0; k < 8; ++k)
          a[q * 8 + k] += bf2f(r0[q][k]) + bf2f(r1[q][k]);
    }
    if (j < cnt) {
      int s0 = eidx[st + j];
      const u16x8* p0 = reinterpret_cast<const u16x8*>(fb + (size_t)s0 * 128);
#pragma unroll
      for (int q = 0; q < 4; ++q) {
        u16x8 r0 = p0[q];
#pragma unroll
        for (int k = 0; k < 8; ++k) a[q * 8 + k] += bf2f(r0[k]);
      }
    }
    // scale + cvt + swizzled ds_write (4 x 16B)
#pragma unroll
    for (int q = 0; q < 4; ++q) {
      u16x8 o;
#pragma unroll
      for (int k = 0; k < 8; ++k) o[k] = f2bf(sc * a[q * 8 + k]);
      int addr = gn * 256 + ((gl * 64 + q * 16) ^ ((gn & 7) << 4));
      *reinterpret_cast<u16x8*>((char*)&Am1[buf][0] + addr) = o;
    }
  };

  const int npan = (NN + 63) >> 6;   // 1563
  int p = blockIdx.x;
  stage(0, p);
  int cur = 0;

#pragma unroll 1
  for (; p < npan; p += gridDim.x) {
    int pn = p + gridDim.x;
    if (pn < npan) stage(cur ^ 1, pn);
    asm volatile("s_waitcnt vmcnt(0) lgkmcnt(0)" ::: "memory");
    __builtin_amdgcn_s_barrier();

    const int row0 = p * 64;
    f32x4 acc[4][4];
#pragma unroll
    for (int fm = 0; fm < 4; ++fm)
#pragma unroll
      for (int fn = 0; fn < 4; ++fn) acc[fm][fn] = (f32x4)0.f;

#pragma unroll
    for (int ks = 0; ks < 8; ++ks) {
      const char* half = (ks < 4) ? (const char*)&Am1[cur][0] : (const char*)&Asf[cur][0];
      i32x4 a[4];
#pragma unroll
      for (int fm = 0; fm < 4; ++fm) {
        int r = fm * 16 + llo;
        int cb = (((ks & 3) * 64 + lhi * 16)) ^ ((r & 7) << 4);
        a[fm] = *reinterpret_cast<const i32x4*>(half + r * 256 + cb);
      }
#pragma unroll
      for (int fm = 0; fm < 4; ++fm)
#pragma unroll
        for (int fn = 0; fn < 4; ++fn)
          asm("v_mfma_f32_16x16x32_bf16 %0, %1, %2, %0"
              : "+v"(acc[fm][fn]) : "v"(a[fm]), "v"(bfrag[ks][fn]));
    }

    asm volatile("s_nop 7\n\ts_nop 7");   // MFMA -> VALU read hazard guard

#pragma unroll
    for (int fm = 0; fm < 4; ++fm) {
#pragma unroll
      for (int fn = 0; fn < 4; ++fn) {
        int col = wave * 64 + fn * 16 + llo;
#pragma unroll
        for (int j = 0; j < 4; ++j) {
          int row = row0 + fm * 16 + lhi * 4 + j;
          if (row < NN) {
            float v = fmaxf(acc[fm][fn][j] + bv[fn], 0.f);
            outb[(size_t)row * 256 + col] = f2bf(v);
          }
        }
      }
    }
    __builtin_amdgcn_s_barrier();
    cur ^= 1;
  }
}

// ---------------- layer-2 persistent bf16 MFMA GEMM (round-7 proven) ----------------
// A=hb [M,256]; B out-concat (W2l|+32768 W2r, each [128,256]);
// waves 0-1 -> outb = bf16(h@W2l) [NN,128]; waves 2-3 -> outb2 = bf16(h@W2r + bias).
__global__ __launch_bounds__(256, 2) void mgemm2_k(
    const unsigned short* __restrict__ A1,
    const unsigned short* __restrict__ Wbase, const float* __restrict__ bias,
    unsigned short* __restrict__ outb, unsigned short* __restrict__ outb2) {
  __shared__ unsigned short As[2][64 * 256];   // 2 x 32 KB, row stride 512 B
  const int t = threadIdx.x;
  const int wave = t >> 6, lane = t & 63;
  const int lhi = lane >> 4, llo = lane & 15;

  i32x4 bfrag[8][4];
  float bv[4];
#pragma unroll
  for (int fn = 0; fn < 4; ++fn) {
    int c = wave * 64 + fn * 16 + llo;
    const unsigned short* rowp = Wbase + (wave >= 2 ? 32768 : 0) + (size_t)(c & 127) * 256;
    bv[fn] = (wave >= 2) ? bias[c & 127] : 0.f;
#pragma unroll
    for (int ks = 0; ks < 8; ++ks)
      bfrag[ks][fn] = *reinterpret_cast<const i32x4*>(rowp + ks * 32 + lhi * 8);
  }

  auto stage = [&](int buf, int row0) {
#pragma unroll
    for (int c = 0; c < 8; ++c) {
      int chunk = wave * 8 + c;
      int tb = chunk * 1024 + lane * 16;
      int r = tb >> 9;
      int cb = tb & 511;
      int cbs = cb ^ ((r & 7) << 4);
      int gr = min(row0 + r, NN - 1);
      __builtin_amdgcn_global_load_lds(
          (const __attribute__((address_space(1))) void*)
              ((const char*)(A1 + (size_t)gr * 256) + cbs),
          (__attribute__((address_space(3))) void*)((char*)As + buf * 32768 + chunk * 1024),
          16, 0, 0);
    }
  };

  const int npan = (NN + 63) >> 6;
  int p = blockIdx.x;
  stage(0, p * 64);
  int cur = 0;

#pragma unroll 1
  for (; p < npan; p += gridDim.x) {
    int pn = p + gridDim.x;
    if (pn < npan) stage(cur ^ 1, pn * 64);
    asm volatile("s_waitcnt vmcnt(8)" ::: "memory");
    __builtin_amdgcn_s_barrier();

    const int row0 = p * 64;
    f32x4 acc[4][4];
#pragma unroll
    for (int fm = 0; fm < 4; ++fm)
#pragma unroll
      for (int fn = 0; fn < 4; ++fn) acc[fm][fn] = (f32x4)0.f;

#pragma unroll
    for (int ks = 0; ks < 8; ++ks) {
      i32x4 a[4];
#pragma unroll
      for (int fm = 0; fm < 4; ++fm) {
        int r = fm * 16 + llo;
        int cb = (ks * 64 + lhi * 16) ^ ((r & 7) << 4);
        a[fm] = *reinterpret_cast<const i32x4*>((const char*)As + cur * 32768 + r * 512 + cb);
      }
#pragma unroll
      for (int fm = 0; fm < 4; ++fm)
#pragma unroll
        for (int fn = 0; fn < 4; ++fn)
          asm("v_mfma_f32_16x16x32_bf16 %0, %1, %2, %0"
              : "+v"(acc[fm][fn]) : "v"(a[fm]), "v"(bfrag[ks][fn]));
    }

    asm volatile("s_nop 7\n\ts_nop 7");

#pragma unroll
    for (int fm = 0; fm < 4; ++fm) {
#pragma unroll
      for (int fn = 0; fn < 4; ++fn) {
        int col = wave * 64 + fn * 16 + llo;
#pragma unroll
        for (int j = 0; j < 4; ++j) {
          int row = row0 + fm * 16 + lhi * 4 + j;
          if (row < NN) {
            float v = acc[fm][fn][j] + bv[fn];
            if (wave < 2) outb[(size_t)row * 128 + col] = f2bf(v);
            else          outb2[(size_t)row * 128 + (col - 128)] = f2bf(v);
          }
        }
      }
    }
    __builtin_amdgcn_s_barrier();
    cur ^= 1;
  }
}

extern "C" void kernel_launch(void* const* d_in, const int* in_sizes, int n_in,
                              void* d_out, int out_size, void* d_ws, size_t ws_size,
                              hipStream_t stream) {
  const float* x   = (const float*)d_in[0];
  const int*   ei  = (const int*)d_in[1];
  const float* W1l = (const float*)d_in[2];
  const float* b1  = (const float*)d_in[3];
  const float* W1r = (const float*)d_in[4];
  const float* W2l = (const float*)d_in[5];
  const float* b2  = (const float*)d_in[6];
  const float* W2r = (const float*)d_in[7];
  float* out = (float*)d_out;

  char* ws = (char*)d_ws;
  float*          inv    = (float*)(ws);
  int*            deg    = (int*)(ws + 0x80000);
  int*            offs   = (int*)(ws + 0x100000);
  int*            bsum   = (int*)(ws + 0x200000);
  unsigned short* Wb     = (unsigned short*)(ws + 0x280000);  // 4 x 32768 bf16, packed
  int*            eidx   = (int*)(ws + 0x400000);
  unsigned short* xb     = (unsigned short*)(ws + 0x800000);   // [NN,128] bf16
  unsigned short* selfb  = (unsigned short*)(ws + 0x2200000);  // [NN,128] bf16
  unsigned short* hb     = (unsigned short*)(ws + 0x3C00000);  // [NN,256] bf16
  unsigned short* hWb    = (unsigned short*)(ws + 0x6E00000);  // [NN,128] bf16
  int*            rord   = (int*)(ws + 0x8600000);             // [NE] int

  const int* src = ei;
  const int* dst = ei + NE;
  const int NB = (NN + 1023) / 1024;  // 98

  // ---- CSR build (fill is atomic-free via degree ordinals) ----
  hipMemsetAsync(deg, 0, NN * sizeof(int), stream);
  degree_k<<<(NE + 255) / 256, 256, 0, stream>>>(dst, deg, rord);
  scan1_k<<<NB, 256, 0, stream>>>(deg, offs, bsum, inv);
  scan2_k<<<1, 256, 0, stream>>>(bsum, NB);
  scan3_k<<<NB, 256, 0, stream>>>(offs, bsum);
  fill_k<<<(NE + 255) / 256, 256, 0, stream>>>(src, dst, offs, rord, eidx);

  // ---- casts ----
  cast_x_k<<<(NN * 128 / 4 + 255) / 256, 256, 0, stream>>>(x, xb);
  cast_w4_k<<<(4 * 32768 + 255) / 256, 256, 0, stream>>>(W1l, W1r, W2l, W2r, Wb);

  // ---- layer 1 FUSED: h = relu([mean-agg(x) | x] @ [W1l|W1r]^T + b1) ----
  fgemm1_k<<<512, 256, 0, stream>>>(xb, offs, deg, inv, eidx, Wb, b1, hb);

  // ---- layer 2 (transform-first): hWb = bf16(h@W2l), selfb = bf16(h@W2r + b2);
  //      out = selfb + inv * gather(hWb) ----
  mgemm2_k<<<512, 256, 0, stream>>>(hb, Wb + 65536, b2, hWb, selfb);
  gather2_k<<<(NN + 15) / 16, 256, 0, stream>>>(hWb, offs, deg, inv, eidx, selfb, out);
}

// Round 10
// 228.805 us; speedup vs baseline: 1.0005x; 1.0005x over previous
//
#include <hip/hip_runtime.h>

#define NN 100000
#define NE 800000

typedef __attribute__((ext_vector_type(4))) float f32x4;
typedef __attribute__((ext_vector_type(4))) int   i32x4;
typedef __attribute__((ext_vector_type(8))) unsigned short u16x8;

__device__ __forceinline__ unsigned short f2bf(float f) {
  unsigned u = __float_as_uint(f);
  return (unsigned short)((u + 0x7FFFu + ((u >> 16) & 1u)) >> 16);
}
__device__ __forceinline__ float bf2f(unsigned short b) {
  return __uint_as_float(((unsigned)b) << 16);
}

// ---------------- CSR build ----------------
__global__ void degree_k(const int* __restrict__ dst, int* __restrict__ deg,
                         int* __restrict__ rord) {
  int e = blockIdx.x * 256 + threadIdx.x;
  if (e < NE) {
    int o = atomicAdd(&deg[dst[e]], 1);
    __builtin_nontemporal_store(o, &rord[e]);
  }
}

__global__ __launch_bounds__(256) void scan1_k(const int* __restrict__ deg,
    int* __restrict__ offs, int* __restrict__ bsum, float* __restrict__ inv) {
  __shared__ int s[256];
  int t = threadIdx.x;
  int base = blockIdx.x * 1024 + t * 4;
  int v[4], tsum = 0;
#pragma unroll
  for (int k = 0; k < 4; ++k) {
    int i = base + k;
    v[k] = (i < NN) ? deg[i] : 0;
    tsum += v[k];
    if (i < NN) inv[i] = 1.0f / fmaxf((float)v[k], 1.0f);
  }
  s[t] = tsum; __syncthreads();
  int val = tsum;
#pragma unroll
  for (int off = 1; off < 256; off <<= 1) {
    int x = (t >= off) ? s[t - off] : 0;
    __syncthreads();
    val += x; s[t] = val;
    __syncthreads();
  }
  int excl = val - tsum;
  if (t == 255) bsum[blockIdx.x] = val;
  int run = excl;
#pragma unroll
  for (int k = 0; k < 4; ++k) { int i = base + k; if (i < NN) offs[i] = run; run += v[k]; }
}

__global__ __launch_bounds__(256) void scan2_k(int* __restrict__ bsum, int nb) {
  __shared__ int s[256];
  int t = threadIdx.x;
  int v = (t < nb) ? bsum[t] : 0;
  s[t] = v; __syncthreads();
  int val = v;
#pragma unroll
  for (int off = 1; off < 256; off <<= 1) {
    int x = (t >= off) ? s[t - off] : 0;
    __syncthreads();
    val += x; s[t] = val;
    __syncthreads();
  }
  if (t < nb) bsum[t] = val - v;
}

__global__ __launch_bounds__(256) void scan3_k(int* __restrict__ offs,
    const int* __restrict__ bsum) {
  int base = blockIdx.x * 1024 + threadIdx.x * 4;
  int add = bsum[blockIdx.x];
#pragma unroll
  for (int k = 0; k < 4; ++k) {
    int i = base + k;
    if (i < NN) offs[i] += add;
  }
}

__global__ void fill_k(const int* __restrict__ src, const int* __restrict__ dst,
    const int* __restrict__ offs, const int* __restrict__ rord,
    int* __restrict__ eidx) {
  int e = blockIdx.x * 256 + threadIdx.x;
  if (e < NE) {
    int p = offs[dst[e]] + rord[e];
    __builtin_nontemporal_store(src[e], &eidx[p]);
  }
}

// ---------------- combined casts: x -> xb, 4 weights -> Wb ----------------
#define NXV (NN * 128 / 4)   // 3200000 float4 chunks
__global__ __launch_bounds__(256) void cast_all_k(const float* __restrict__ x,
    const float* __restrict__ Wa, const float* __restrict__ Wbm,
    const float* __restrict__ Wc, const float* __restrict__ Wd,
    unsigned short* __restrict__ xb, unsigned short* __restrict__ Wbo) {
  int i = blockIdx.x * 256 + threadIdx.x;
  if (i < NXV) {
    float4 v = *reinterpret_cast<const float4*>(x + (size_t)i * 4);
    ushort4 o;
    o.x = f2bf(v.x); o.y = f2bf(v.y); o.z = f2bf(v.z); o.w = f2bf(v.w);
    *reinterpret_cast<ushort4*>(xb + (size_t)i * 4) = o;
  } else {
    int k = i - NXV;
    if (k < 4 * 32768) {
      int seg = k >> 15, off = k & 32767;
      const float* s = (seg < 2) ? (seg == 0 ? Wa : Wbm) : (seg == 2 ? Wc : Wd);
      Wbo[k] = f2bf(s[off]);
    }
  }
}

// ---------------- gather (bf16 table, fp32 accum, deep ILP) ----------------
// 16 lanes/node, 16B (8 bf16) per lane; unroll x8 + x4 + scalar tails so up to
// 8 independent row-loads are in flight per lane (round-7 had 4).
// GMODE 0: outb(bf16)[node] = bf16(inv*sum(feat[nbr]))
// GMODE 2: outf(f32)[node]  = bf2f(selfb[node]) + inv*sum(feat[nbr])
template<int GMODE>
__global__ __launch_bounds__(256) void gather_k(const unsigned short* __restrict__ feat,
    const int* __restrict__ offs, const int* __restrict__ deg,
    const float* __restrict__ inv, const int* __restrict__ eidx,
    const unsigned short* __restrict__ selfb,
    unsigned short* __restrict__ outb, float* __restrict__ outf) {
  int node = blockIdx.x * 16 + (threadIdx.x >> 4);
  int l = threadIdx.x & 15;
  if (node >= NN) return;
  int st = offs[node], n = deg[node];
  float a[8];
#pragma unroll
  for (int k = 0; k < 8; ++k) a[k] = 0.f;

  int j = 0;
  for (; j + 8 <= n; j += 8) {
    int si[8];
#pragma unroll
    for (int q = 0; q < 8; ++q) si[q] = eidx[st + j + q];
    u16x8 r[8];
#pragma unroll
    for (int q = 0; q < 8; ++q)
      r[q] = *reinterpret_cast<const u16x8*>(feat + (size_t)si[q] * 128 + l * 8);
#pragma unroll
    for (int q = 0; q < 8; ++q)
#pragma unroll
      for (int k = 0; k < 8; ++k) a[k] += bf2f(r[q][k]);
  }
  for (; j + 4 <= n; j += 4) {
    int si[4];
#pragma unroll
    for (int q = 0; q < 4; ++q) si[q] = eidx[st + j + q];
    u16x8 r[4];
#pragma unroll
    for (int q = 0; q < 4; ++q)
      r[q] = *reinterpret_cast<const u16x8*>(feat + (size_t)si[q] * 128 + l * 8);
#pragma unroll
    for (int q = 0; q < 4; ++q)
#pragma unroll
      for (int k = 0; k < 8; ++k) a[k] += bf2f(r[q][k]);
  }
  for (; j < n; ++j) {
    int s = eidx[st + j];
    u16x8 r = *reinterpret_cast<const u16x8*>(feat + (size_t)s * 128 + l * 8);
#pragma unroll
    for (int k = 0; k < 8; ++k) a[k] += bf2f(r[k]);
  }

  float sc = inv[node];
  if (GMODE == 2) {
    u16x8 sb = *reinterpret_cast<const u16x8*>(selfb + (size_t)node * 128 + l * 8);
    float4 o0, o1;
    o0.x = bf2f(sb[0]) + sc * a[0]; o0.y = bf2f(sb[1]) + sc * a[1];
    o0.z = bf2f(sb[2]) + sc * a[2]; o0.w = bf2f(sb[3]) + sc * a[3];
    o1.x = bf2f(sb[4]) + sc * a[4]; o1.y = bf2f(sb[5]) + sc * a[5];
    o1.z = bf2f(sb[6]) + sc * a[6]; o1.w = bf2f(sb[7]) + sc * a[7];
    float* po = outf + (size_t)node * 128 + l * 8;
    *reinterpret_cast<float4*>(po) = o0;
    *reinterpret_cast<float4*>(po + 4) = o1;
  } else {
    u16x8 o;
#pragma unroll
    for (int k = 0; k < 8; ++k) o[k] = f2bf(sc * a[k]);
    *reinterpret_cast<u16x8*>(outb + (size_t)node * 128 + l * 8) = o;
  }
}

// ---------------- persistent bf16 MFMA GEMM (64 rows x 256 cols / panel) --------
// Grid = 512 persistent blocks (2/CU, 64KB LDS dbuf). B fragments preloaded once.
// Panel loop: stage(next)->vmcnt(8) counted->raw barrier->MFMA+stores->raw barrier.
// MODE 0 (layer 1): A=[A1|A2] k-concat; B k-concat; out = bf16 relu(C+bias) -> outb [NN,256].
// MODE 1 (layer 2): A=A1 [M,256]; B out-concat; waves 0-1 -> outb = bf16(h@W2l) [NN,128];
//   waves 2-3 -> outb2 = bf16(h@W2r + bias) [NN,128].
template<int MODE>
__global__ __launch_bounds__(256, 2) void mgemm_k(
    const unsigned short* __restrict__ A1, const unsigned short* __restrict__ A2,
    const unsigned short* __restrict__ Wbase, const float* __restrict__ bias,
    unsigned short* __restrict__ outb, unsigned short* __restrict__ outb2) {
  __shared__ unsigned short As[2][64 * 256];   // 2 x 32 KB, row stride 512 B
  const int t = threadIdx.x;
  const int wave = t >> 6, lane = t & 63;
  const int lhi = lane >> 4, llo = lane & 15;

  // ---- B fragments + bias, loaded once (weights are L2-resident) ----
  i32x4 bfrag[8][4];
  float bv[4];
#pragma unroll
  for (int fn = 0; fn < 4; ++fn) {
    int c = wave * 64 + fn * 16 + llo;
    const unsigned short* rowp;
    if (MODE == 0) {
      rowp = Wbase + (size_t)c * 128;
      bv[fn] = bias[c];
    } else {
      rowp = Wbase + (wave >= 2 ? 32768 : 0) + (size_t)(c & 127) * 256;
      bv[fn] = (wave >= 2) ? bias[c & 127] : 0.f;
    }
#pragma unroll
    for (int ks = 0; ks < 8; ++ks) {
      int koff = (MODE == 0) ? ((ks & 3) * 32 + lhi * 8 + ((ks >= 4) ? 32768 : 0))
                             : (ks * 32 + lhi * 8);
      bfrag[ks][fn] = *reinterpret_cast<const i32x4*>(rowp + koff);
    }
  }

  auto stage = [&](int buf, int row0) {
#pragma unroll
    for (int c = 0; c < 8; ++c) {
      int chunk = wave * 8 + c;
      int tb = chunk * 1024 + lane * 16;
      int r = tb >> 9;
      int cb = tb & 511;
      int cbs = cb ^ ((r & 7) << 4);     // involutive XOR swizzle (bits 4-6)
      int gr = min(row0 + r, NN - 1);
      const char* gsrc;
      if (MODE == 0) {
        const unsigned short* Asel = (cbs < 256) ? A1 : A2;
        gsrc = (const char*)(Asel + (size_t)gr * 128) + (cbs & 255);
      } else {
        gsrc = (const char*)(A1 + (size_t)gr * 256) + cbs;
      }
      __builtin_amdgcn_global_load_lds(
          (const __attribute__((address_space(1))) void*)gsrc,
          (__attribute__((address_space(3))) void*)((char*)As + buf * 32768 + chunk * 1024),
          16, 0, 0);
    }
  };

  const int npan = (NN + 63) >> 6;   // 1563
  int p = blockIdx.x;
  stage(0, p * 64);
  int cur = 0;

#pragma unroll 1
  for (; p < npan; p += gridDim.x) {
    int pn = p + gridDim.x;
    if (pn < npan) stage(cur ^ 1, pn * 64);
    // counted wait: in-order retirement => <=8 outstanding means current buffer's
    // 8 loads (issued before the 8 just staged) have landed. Never drains to 0.
    asm volatile("s_waitcnt vmcnt(8)" ::: "memory");
    __builtin_amdgcn_s_barrier();

    const int row0 = p * 64;
    f32x4 acc[4][4];
#pragma unroll
    for (int fm = 0; fm < 4; ++fm)
#pragma unroll
      for (int fn = 0; fn < 4; ++fn) acc[fm][fn] = (f32x4)0.f;

#pragma unroll
    for (int ks = 0; ks < 8; ++ks) {
      i32x4 a[4];
#pragma unroll
      for (int fm = 0; fm < 4; ++fm) {
        int r = fm * 16 + llo;
        int cb = (ks * 64 + lhi * 16) ^ ((r & 7) << 4);
        a[fm] = *reinterpret_cast<const i32x4*>((const char*)As + cur * 32768 + r * 512 + cb);
      }
#pragma unroll
      for (int fm = 0; fm < 4; ++fm)
#pragma unroll
        for (int fn = 0; fn < 4; ++fn)
          asm("v_mfma_f32_16x16x32_bf16 %0, %1, %2, %0"
              : "+v"(acc[fm][fn]) : "v"(a[fm]), "v"(bfrag[ks][fn]));
    }

    asm volatile("s_nop 7\n\ts_nop 7");   // MFMA -> VALU read hazard guard

#pragma unroll
    for (int fm = 0; fm < 4; ++fm) {
#pragma unroll
      for (int fn = 0; fn < 4; ++fn) {
        int col = wave * 64 + fn * 16 + llo;
#pragma unroll
        for (int j = 0; j < 4; ++j) {
          int row = row0 + fm * 16 + lhi * 4 + j;
          if (row < NN) {
            float v = acc[fm][fn][j] + bv[fn];
            if (MODE == 0) {
              v = fmaxf(v, 0.f);
              outb[(size_t)row * 256 + col] = f2bf(v);
            } else if (wave < 2) {
              outb[(size_t)row * 128 + col] = f2bf(v);
            } else {
              outb2[(size_t)row * 128 + (col - 128)] = f2bf(v);
            }
          }
        }
      }
    }
    __builtin_amdgcn_s_barrier();  // all waves done reading As[cur] before restage
    cur ^= 1;
  }
}

extern "C" void kernel_launch(void* const* d_in, const int* in_sizes, int n_in,
                              void* d_out, int out_size, void* d_ws, size_t ws_size,
                              hipStream_t stream) {
  const float* x   = (const float*)d_in[0];
  const int*   ei  = (const int*)d_in[1];
  const float* W1l = (const float*)d_in[2];
  const float* b1  = (const float*)d_in[3];
  const float* W1r = (const float*)d_in[4];
  const float* W2l = (const float*)d_in[5];
  const float* b2  = (const float*)d_in[6];
  const float* W2r = (const float*)d_in[7];
  float* out = (float*)d_out;

  char* ws = (char*)d_ws;
  float*          inv    = (float*)(ws);
  int*            deg    = (int*)(ws + 0x80000);
  int*            offs   = (int*)(ws + 0x100000);
  int*            bsum   = (int*)(ws + 0x200000);
  unsigned short* Wb     = (unsigned short*)(ws + 0x280000);  // 4 x 32768 bf16, packed
  int*            eidx   = (int*)(ws + 0x400000);
  unsigned short* xb     = (unsigned short*)(ws + 0x800000);   // [NN,128] bf16
  unsigned short* m1b    = (unsigned short*)(ws + 0x2200000);  // [NN,128] bf16; selfb in layer 2
  unsigned short* hb     = (unsigned short*)(ws + 0x3C00000);  // [NN,256] bf16
  unsigned short* hWb    = (unsigned short*)(ws + 0x6E00000);  // [NN,128] bf16
  int*            rord   = (int*)(ws + 0x8600000);             // [NE] int
  unsigned short* selfb  = m1b;   // m1b dead after layer-1 GEMM

  const int* src = ei;
  const int* dst = ei + NE;
  const int NB = (NN + 1023) / 1024;  // 98

  // ---- CSR build (fill is atomic-free via degree ordinals) ----
  hipMemsetAsync(deg, 0, NN * sizeof(int), stream);
  degree_k<<<(NE + 255) / 256, 256, 0, stream>>>(dst, deg, rord);
  scan1_k<<<NB, 256, 0, stream>>>(deg, offs, bsum, inv);
  scan2_k<<<1, 256, 0, stream>>>(bsum, NB);
  scan3_k<<<NB, 256, 0, stream>>>(offs, bsum);
  fill_k<<<(NE + 255) / 256, 256, 0, stream>>>(src, dst, offs, rord, eidx);

  // ---- casts (single dispatch) ----
  cast_all_k<<<(NXV + 4 * 32768 + 255) / 256, 256, 0, stream>>>(x, W1l, W1r, W2l, W2r, xb, Wb);

  // ---- layer 1: m1 = gather(x); h = relu([m1|x] @ [W1l|W1r]^T + b1) ----
  gather_k<0><<<(NN + 15) / 16, 256, 0, stream>>>(xb, offs, deg, inv, eidx, nullptr, m1b, nullptr);
  mgemm_k<0><<<512, 256, 0, stream>>>(m1b, xb, Wb, b1, hb, nullptr);

  // ---- layer 2 (transform-first): hWb = bf16(h@W2l), selfb = bf16(h@W2r + b2);
  //      out = selfb + inv * gather(hWb) ----
  mgemm_k<1><<<512, 256, 0, stream>>>(hb, nullptr, Wb + 65536, b2, hWb, selfb);
  gather_k<2><<<(NN + 15) / 16, 256, 0, stream>>>(hWb, offs, deg, inv, eidx, selfb, nullptr, out);
}

// Round 11
// 224.923 us; speedup vs baseline: 1.0178x; 1.0173x over previous
//
#include <hip/hip_runtime.h>

#define NN 100000
#define NE 800000

typedef __attribute__((ext_vector_type(4))) float f32x4;
typedef __attribute__((ext_vector_type(4))) int   i32x4;
typedef __attribute__((ext_vector_type(8))) unsigned short u16x8;

__device__ __forceinline__ unsigned short f2bf(float f) {
  unsigned u = __float_as_uint(f);
  return (unsigned short)((u + 0x7FFFu + ((u >> 16) & 1u)) >> 16);
}
__device__ __forceinline__ float bf2f(unsigned short b) {
  return __uint_as_float(((unsigned)b) << 16);
}

// ---------------- fused prologue: degree (atomics) + x cast + W cast ----------------
// Degree blocks first: their atomic-latency chain hides under the cast streaming.
#define NBDEG 3125                   // 800000 / 256
#define NXV   (NN * 128 / 4)         // 3200000 float4 chunks
#define NBX   12500                  // NXV / 256
#define NBW   512                    // 131072 / 256
__global__ __launch_bounds__(256) void prep_k(
    const float* __restrict__ x,
    const float* __restrict__ Wa, const float* __restrict__ Wbm,
    const float* __restrict__ Wc, const float* __restrict__ Wd,
    const int* __restrict__ dst,
    unsigned short* __restrict__ xb, unsigned short* __restrict__ Wbo,
    int* __restrict__ deg, int* __restrict__ rord) {
  int bid = blockIdx.x, t = threadIdx.x;
  if (bid < NBDEG) {
    int e = bid * 256 + t;
    int o = atomicAdd(&deg[dst[e]], 1);
    __builtin_nontemporal_store(o, &rord[e]);
  } else if (bid < NBDEG + NBX) {
    int i = (bid - NBDEG) * 256 + t;
    float4 v = *reinterpret_cast<const float4*>(x + (size_t)i * 4);
    ushort4 o;
    o.x = f2bf(v.x); o.y = f2bf(v.y); o.z = f2bf(v.z); o.w = f2bf(v.w);
    *reinterpret_cast<ushort4*>(xb + (size_t)i * 4) = o;
  } else {
    int k = (bid - NBDEG - NBX) * 256 + t;
    int seg = k >> 15, off = k & 32767;
    const float* s = (seg < 2) ? (seg == 0 ? Wa : Wbm) : (seg == 2 ? Wc : Wd);
    Wbo[k] = f2bf(s[off]);
  }
}

// ---------------- CSR scans ----------------
__global__ __launch_bounds__(256) void scan1_k(const int* __restrict__ deg,
    int* __restrict__ offs, int* __restrict__ bsum, float* __restrict__ inv) {
  __shared__ int s[256];
  int t = threadIdx.x;
  int base = blockIdx.x * 1024 + t * 4;
  int v[4], tsum = 0;
#pragma unroll
  for (int k = 0; k < 4; ++k) {
    int i = base + k;
    v[k] = (i < NN) ? deg[i] : 0;
    tsum += v[k];
    if (i < NN) inv[i] = 1.0f / fmaxf((float)v[k], 1.0f);
  }
  s[t] = tsum; __syncthreads();
  int val = tsum;
#pragma unroll
  for (int off = 1; off < 256; off <<= 1) {
    int x = (t >= off) ? s[t - off] : 0;
    __syncthreads();
    val += x; s[t] = val;
    __syncthreads();
  }
  int excl = val - tsum;
  if (t == 255) bsum[blockIdx.x] = val;
  int run = excl;
#pragma unroll
  for (int k = 0; k < 4; ++k) { int i = base + k; if (i < NN) offs[i] = run; run += v[k]; }
}

__global__ __launch_bounds__(256) void scan2_k(int* __restrict__ bsum, int nb) {
  __shared__ int s[256];
  int t = threadIdx.x;
  int v = (t < nb) ? bsum[t] : 0;
  s[t] = v; __syncthreads();
  int val = v;
#pragma unroll
  for (int off = 1; off < 256; off <<= 1) {
    int x = (t >= off) ? s[t - off] : 0;
    __syncthreads();
    val += x; s[t] = val;
    __syncthreads();
  }
  if (t < nb) bsum[t] = val - v;
}

// ---------------- fused: finalize offs (-> offs2, separate buffer: no race) + fill ----
// fill reads PARTIAL offs + bsum[dst>>10]; finalize blocks write offs2 only.
#define NBFIN 98                     // ceil(NN/1024)
__global__ __launch_bounds__(256) void finfill_k(
    const int* __restrict__ offs, const int* __restrict__ bsum,
    int* __restrict__ offs2,
    const int* __restrict__ src, const int* __restrict__ dst,
    const int* __restrict__ rord, int* __restrict__ eidx) {
  int bid = blockIdx.x, t = threadIdx.x;
  if (bid < NBFIN) {
    int base = bid * 1024 + t * 4;
    int add = bsum[bid];
#pragma unroll
    for (int k = 0; k < 4; ++k) {
      int i = base + k;
      if (i < NN) offs2[i] = offs[i] + add;
    }
  } else {
    int e = (bid - NBFIN) * 256 + t;
    if (e < NE) {
      int d = dst[e];
      int p = offs[d] + bsum[d >> 10] + rord[e];
      __builtin_nontemporal_store(src[e], &eidx[p]);
    }
  }
}

// ---------------- gather (bf16 table, fp32 accum, deep ILP, grid-stride) ----------------
// 16 lanes/node, 16B (8 bf16) per lane; unroll x8 + x4 + scalar tails.
// GMODE 0: outb(bf16)[node] = bf16(inv*sum(feat[nbr]))
// GMODE 2: outf(f32)[node]  = bf2f(selfb[node]) + inv*sum(feat[nbr])  (nt store)
template<int GMODE>
__global__ __launch_bounds__(256) void gather_k(const unsigned short* __restrict__ feat,
    const int* __restrict__ offs, const int* __restrict__ deg,
    const float* __restrict__ inv, const int* __restrict__ eidx,
    const unsigned short* __restrict__ selfb,
    unsigned short* __restrict__ outb, float* __restrict__ outf) {
  const int l = threadIdx.x & 15;
  for (int nb = blockIdx.x * 16; nb < NN; nb += gridDim.x * 16) {
    int node = nb + (threadIdx.x >> 4);
    if (node >= NN) continue;
    int st = offs[node], n = deg[node];
    float a[8];
#pragma unroll
    for (int k = 0; k < 8; ++k) a[k] = 0.f;

    int j = 0;
    for (; j + 8 <= n; j += 8) {
      int si[8];
#pragma unroll
      for (int q = 0; q < 8; ++q) si[q] = eidx[st + j + q];
      u16x8 r[8];
#pragma unroll
      for (int q = 0; q < 8; ++q)
        r[q] = *reinterpret_cast<const u16x8*>(feat + (size_t)si[q] * 128 + l * 8);
#pragma unroll
      for (int q = 0; q < 8; ++q)
#pragma unroll
        for (int k = 0; k < 8; ++k) a[k] += bf2f(r[q][k]);
    }
    for (; j + 4 <= n; j += 4) {
      int si[4];
#pragma unroll
      for (int q = 0; q < 4; ++q) si[q] = eidx[st + j + q];
      u16x8 r[4];
#pragma unroll
      for (int q = 0; q < 4; ++q)
        r[q] = *reinterpret_cast<const u16x8*>(feat + (size_t)si[q] * 128 + l * 8);
#pragma unroll
      for (int q = 0; q < 4; ++q)
#pragma unroll
        for (int k = 0; k < 8; ++k) a[k] += bf2f(r[q][k]);
    }
    for (; j < n; ++j) {
      int s = eidx[st + j];
      u16x8 r = *reinterpret_cast<const u16x8*>(feat + (size_t)s * 128 + l * 8);
#pragma unroll
      for (int k = 0; k < 8; ++k) a[k] += bf2f(r[k]);
    }

    float sc = inv[node];
    if (GMODE == 2) {
      u16x8 sb = *reinterpret_cast<const u16x8*>(selfb + (size_t)node * 128 + l * 8);
      f32x4 o0, o1;
      o0[0] = bf2f(sb[0]) + sc * a[0]; o0[1] = bf2f(sb[1]) + sc * a[1];
      o0[2] = bf2f(sb[2]) + sc * a[2]; o0[3] = bf2f(sb[3]) + sc * a[3];
      o1[0] = bf2f(sb[4]) + sc * a[4]; o1[1] = bf2f(sb[5]) + sc * a[5];
      o1[2] = bf2f(sb[6]) + sc * a[6]; o1[3] = bf2f(sb[7]) + sc * a[7];
      float* po = outf + (size_t)node * 128 + l * 8;
      __builtin_nontemporal_store(o0, reinterpret_cast<f32x4*>(po));
      __builtin_nontemporal_store(o1, reinterpret_cast<f32x4*>(po + 4));
    } else {
      u16x8 o;
#pragma unroll
      for (int k = 0; k < 8; ++k) o[k] = f2bf(sc * a[k]);
      *reinterpret_cast<u16x8*>(outb + (size_t)node * 128 + l * 8) = o;
    }
  }
}

// ---------------- persistent bf16 MFMA GEMM (64 rows x 256 cols / panel) --------
// Grid = 512 persistent blocks (2/CU, 64KB LDS dbuf). B fragments preloaded once.
// Panel loop: stage(next)->vmcnt(8) counted->raw barrier->MFMA+stores->raw barrier.
// MODE 0 (layer 1): A=[A1|A2] k-concat; B k-concat; out = bf16 relu(C+bias) -> outb [NN,256].
// MODE 1 (layer 2): A=A1 [M,256]; B out-concat; waves 0-1 -> outb = bf16(h@W2l) [NN,128];
//   waves 2-3 -> outb2 = bf16(h@W2r + bias) [NN,128].
template<int MODE>
__global__ __launch_bounds__(256, 2) void mgemm_k(
    const unsigned short* __restrict__ A1, const unsigned short* __restrict__ A2,
    const unsigned short* __restrict__ Wbase, const float* __restrict__ bias,
    unsigned short* __restrict__ outb, unsigned short* __restrict__ outb2) {
  __shared__ unsigned short As[2][64 * 256];   // 2 x 32 KB, row stride 512 B
  const int t = threadIdx.x;
  const int wave = t >> 6, lane = t & 63;
  const int lhi = lane >> 4, llo = lane & 15;

  // ---- B fragments + bias, loaded once (weights are L2-resident) ----
  i32x4 bfrag[8][4];
  float bv[4];
#pragma unroll
  for (int fn = 0; fn < 4; ++fn) {
    int c = wave * 64 + fn * 16 + llo;
    const unsigned short* rowp;
    if (MODE == 0) {
      rowp = Wbase + (size_t)c * 128;
      bv[fn] = bias[c];
    } else {
      rowp = Wbase + (wave >= 2 ? 32768 : 0) + (size_t)(c & 127) * 256;
      bv[fn] = (wave >= 2) ? bias[c & 127] : 0.f;
    }
#pragma unroll
    for (int ks = 0; ks < 8; ++ks) {
      int koff = (MODE == 0) ? ((ks & 3) * 32 + lhi * 8 + ((ks >= 4) ? 32768 : 0))
                             : (ks * 32 + lhi * 8);
      bfrag[ks][fn] = *reinterpret_cast<const i32x4*>(rowp + koff);
    }
  }

  auto stage = [&](int buf, int row0) {
#pragma unroll
    for (int c = 0; c < 8; ++c) {
      int chunk = wave * 8 + c;
      int tb = chunk * 1024 + lane * 16;
      int r = tb >> 9;
      int cb = tb & 511;
      int cbs = cb ^ ((r & 7) << 4);     // involutive XOR swizzle (bits 4-6)
      int gr = min(row0 + r, NN - 1);
      const char* gsrc;
      if (MODE == 0) {
        const unsigned short* Asel = (cbs < 256) ? A1 : A2;
        gsrc = (const char*)(Asel + (size_t)gr * 128) + (cbs & 255);
      } else {
        gsrc = (const char*)(A1 + (size_t)gr * 256) + cbs;
      }
      __builtin_amdgcn_global_load_lds(
          (const __attribute__((address_space(1))) void*)gsrc,
          (__attribute__((address_space(3))) void*)((char*)As + buf * 32768 + chunk * 1024),
          16, 0, 0);
    }
  };

  const int npan = (NN + 63) >> 6;   // 1563
  int p = blockIdx.x;
  stage(0, p * 64);
  int cur = 0;

#pragma unroll 1
  for (; p < npan; p += gridDim.x) {
    int pn = p + gridDim.x;
    if (pn < npan) stage(cur ^ 1, pn * 64);
    // counted wait: in-order retirement => <=8 outstanding means current buffer's
    // 8 loads (issued before the 8 just staged) have landed. Never drains to 0.
    asm volatile("s_waitcnt vmcnt(8)" ::: "memory");
    __builtin_amdgcn_s_barrier();

    const int row0 = p * 64;
    f32x4 acc[4][4];
#pragma unroll
    for (int fm = 0; fm < 4; ++fm)
#pragma unroll
      for (int fn = 0; fn < 4; ++fn) acc[fm][fn] = (f32x4)0.f;

#pragma unroll
    for (int ks = 0; ks < 8; ++ks) {
      i32x4 a[4];
#pragma unroll
      for (int fm = 0; fm < 4; ++fm) {
        int r = fm * 16 + llo;
        int cb = (ks * 64 + lhi * 16) ^ ((r & 7) << 4);
        a[fm] = *reinterpret_cast<const i32x4*>((const char*)As + cur * 32768 + r * 512 + cb);
      }
#pragma unroll
      for (int fm = 0; fm < 4; ++fm)
#pragma unroll
        for (int fn = 0; fn < 4; ++fn)
          asm("v_mfma_f32_16x16x32_bf16 %0, %1, %2, %0"
              : "+v"(acc[fm][fn]) : "v"(a[fm]), "v"(bfrag[ks][fn]));
    }

    asm volatile("s_nop 7\n\ts_nop 7");   // MFMA -> VALU read hazard guard

#pragma unroll
    for (int fm = 0; fm < 4; ++fm) {
#pragma unroll
      for (int fn = 0; fn < 4; ++fn) {
        int col = wave * 64 + fn * 16 + llo;
#pragma unroll
        for (int j = 0; j < 4; ++j) {
          int row = row0 + fm * 16 + lhi * 4 + j;
          if (row < NN) {
            float v = acc[fm][fn][j] + bv[fn];
            if (MODE == 0) {
              v = fmaxf(v, 0.f);
              outb[(size_t)row * 256 + col] = f2bf(v);
            } else if (wave < 2) {
              outb[(size_t)row * 128 + col] = f2bf(v);
            } else {
              outb2[(size_t)row * 128 + (col - 128)] = f2bf(v);
            }
          }
        }
      }
    }
    __builtin_amdgcn_s_barrier();  // all waves done reading As[cur] before restage
    cur ^= 1;
  }
}

extern "C" void kernel_launch(void* const* d_in, const int* in_sizes, int n_in,
                              void* d_out, int out_size, void* d_ws, size_t ws_size,
                              hipStream_t stream) {
  const float* x   = (const float*)d_in[0];
  const int*   ei  = (const int*)d_in[1];
  const float* W1l = (const float*)d_in[2];
  const float* b1  = (const float*)d_in[3];
  const float* W1r = (const float*)d_in[4];
  const float* W2l = (const float*)d_in[5];
  const float* b2  = (const float*)d_in[6];
  const float* W2r = (const float*)d_in[7];
  float* out = (float*)d_out;

  char* ws = (char*)d_ws;
  float*          inv    = (float*)(ws);
  int*            deg    = (int*)(ws + 0x80000);
  int*            offs   = (int*)(ws + 0x100000);   // partial (scan1)
  int*            offs2  = (int*)(ws + 0x180000);   // finalized
  int*            bsum   = (int*)(ws + 0x200000);
  unsigned short* Wb     = (unsigned short*)(ws + 0x280000);  // 4 x 32768 bf16, packed
  int*            eidx   = (int*)(ws + 0x400000);
  unsigned short* xb     = (unsigned short*)(ws + 0x800000);   // [NN,128] bf16
  unsigned short* m1b    = (unsigned short*)(ws + 0x2200000);  // [NN,128] bf16; selfb in layer 2
  unsigned short* hb     = (unsigned short*)(ws + 0x3C00000);  // [NN,256] bf16
  unsigned short* hWb    = (unsigned short*)(ws + 0x6E00000);  // [NN,128] bf16
  int*            rord   = (int*)(ws + 0x8600000);             // [NE] int
  unsigned short* selfb  = m1b;   // m1b dead after layer-1 GEMM

  const int* src = ei;
  const int* dst = ei + NE;
  const int NB = (NN + 1023) / 1024;  // 98

  // ---- fused prologue: degree (atomics) overlapped with x/W casts ----
  hipMemsetAsync(deg, 0, NN * sizeof(int), stream);
  prep_k<<<NBDEG + NBX + NBW, 256, 0, stream>>>(x, W1l, W1r, W2l, W2r, dst,
                                                xb, Wb, deg, rord);
  scan1_k<<<NB, 256, 0, stream>>>(deg, offs, bsum, inv);
  scan2_k<<<1, 256, 0, stream>>>(bsum, NB);
  // finalize offs -> offs2 (for gathers) fused with atomic-free fill (reads partial offs)
  finfill_k<<<NBFIN + (NE + 255) / 256, 256, 0, stream>>>(offs, bsum, offs2,
                                                          src, dst, rord, eidx);

  // ---- layer 1: m1 = gather(x); h = relu([m1|x] @ [W1l|W1r]^T + b1) ----
  gather_k<0><<<2048, 256, 0, stream>>>(xb, offs2, deg, inv, eidx, nullptr, m1b, nullptr);
  mgemm_k<0><<<512, 256, 0, stream>>>(m1b, xb, Wb, b1, hb, nullptr);

  // ---- layer 2 (transform-first): hWb = bf16(h@W2l), selfb = bf16(h@W2r + b2);
  //      out = selfb + inv * gather(hWb) ----
  mgemm_k<1><<<512, 256, 0, stream>>>(hb, nullptr, Wb + 65536, b2, hWb, selfb);
  gather_k<2><<<2048, 256, 0, stream>>>(hWb, offs2, deg, inv, eidx, selfb, nullptr, out);
}